// Round 14
// baseline (2063.304 us; speedup 1.0000x reference)
//
#include <hip/hip_runtime.h>
#include <cstdint>
#include <cstddef>

#define NB_TOT 1024
#define NANT 64
#define MM 16
#define MPAD 33   // big pad: LDS ~87KB -> only 1 workgroup/CU fits -> compiler targets 4 waves/SIMD -> VGPR budget 128, no spill-for-occupancy. 33%32==1 keeps strided reads conflict-free.
#define DA 4096
#define MAXIT 20
#define SPB 4     // samples per block
#define NTHR 1024 // 16 waves
#define JCOLS 4   // consecutive cols per thread: a = tid*4 + j
#define L_CONST 10.0f

__global__ __launch_bounds__(NTHR, 4)
void mpnet_kernel(const float* __restrict__ x_re, const float* __restrict__ x_im,
                  const float* __restrict__ xm_re, const float* __restrict__ xm_im,
                  const float* __restrict__ M_re, const float* __restrict__ M_im,
                  const float* __restrict__ W_re, const float* __restrict__ W_im,
                  const float* __restrict__ sigma,
                  float* __restrict__ out, int outn_i)
{
  __shared__ float Msh_re[SPB][NANT][MPAD];   // 33.8 KB
  __shared__ float Msh_im[SPB][NANT][MPAD];   // 33.8 KB
  __shared__ float tsh[NANT][8];              // 2 KB, 32B rows (float4-aligned)
  __shared__ float einv_sh[DA];               // 16 KB
  __shared__ float rsd_re[SPB][MM], rsd_im[SPB][MM];
  __shared__ float resh_re[SPB][NANT], resh_im[SPB][NANT];
  __shared__ float red_c2[16][SPB];
  __shared__ int   red_ix[16][SPB];
  __shared__ int   sel_ix[SPB];
  __shared__ float sel_vr[SPB], sel_vi[SPB], sel_md[SPB];
  __shared__ float rn2_sh[SPB], thr_sh[SPB];
  __shared__ int   actsh[SPB];
  __shared__ int   any_act;

  const int tid = threadIdx.x;
  const int b0 = blockIdx.x * SPB;
  const size_t outn = (size_t)outn_i;

  // ---- init: stage M, residual(=x), res(=xm), thresholds
  for (int k2 = 0; k2 < 4; k2++){
    int idx = k2*NTHR + tid;            // 0..4095 = 4 samples x 64 n x 16 m
    int s = idx >> 10, rem = idx & 1023;
    int n = rem >> 4, m = rem & 15;
    Msh_re[s][n][m] = M_re[(size_t)b0*1024 + idx];
    Msh_im[s][n][m] = M_im[(size_t)b0*1024 + idx];
  }
  if (tid < SPB*MM){
    int s = tid >> 4, m = tid & 15;
    rsd_re[s][m] = x_re[(b0+s)*MM + m];
    rsd_im[s][m] = x_im[(b0+s)*MM + m];
  } else if (tid >= 64 && tid < 64 + SPB*NANT){
    int q = tid - 64, s = q >> 6, n = q & 63;
    resh_re[s][n] = xm_re[(b0+s)*NANT + n];
    resh_im[s][n] = xm_im[(b0+s)*NANT + n];
  } else if (tid >= 448 && tid < 448 + SPB){
    int s = tid - 448;
    float sg = sigma[b0+s];
    thr_sh[s] = ((sg*sg) * (float)NANT) * L_CONST;
    actsh[s] = 1;
  }

  // ---- phase 0: E column inverse norms (thread owns cols tid*4..+3)
  {
    float w2x=0.f, w2y=0.f, w2z=0.f, w2w=0.f;
    for (int n = 0; n < NANT; n++){
      float4 wr = *(const float4*)(W_re + (size_t)n*DA + (tid<<2));
      float4 wi = *(const float4*)(W_im + (size_t)n*DA + (tid<<2));
      w2x += wr.x*wr.x + wi.x*wi.x;
      w2y += wr.y*wr.y + wi.y*wi.y;
      w2z += wr.z*wr.z + wi.z*wi.z;
      w2w += wr.w*wr.w + wi.w*wi.w;
    }
    einv_sh[(tid<<2)+0] = 1.f/sqrtf(w2x);
    einv_sh[(tid<<2)+1] = 1.f/sqrtf(w2y);
    einv_sh[(tid<<2)+2] = 1.f/sqrtf(w2z);
    einv_sh[(tid<<2)+3] = 1.f/sqrtf(w2w);
  }
  __syncthreads();

  // ---- phase 1: md = 1/||M_D col||; j split into 2 passes of 2 cols (32 accum regs)
  float md[SPB*JCOLS];   // md[s*4+j], static indexing only
  #pragma unroll
  for (int s = 0; s < SPB; s++){
    #pragma unroll
    for (int jc = 0; jc < 2; jc++){     // cols a = tid*4 + jc*2 + {0,1}
      float nrm0 = 0.f, nrm1 = 0.f;
      #pragma unroll
      for (int mc = 0; mc < 2; mc++){
        float cr0[8], ci0[8], cr1[8], ci1[8];
        #pragma unroll
        for (int q = 0; q < 8; q++){ cr0[q]=0.f; ci0[q]=0.f; cr1[q]=0.f; ci1[q]=0.f; }
        for (int n = 0; n < NANT; n++){
          float2 w_r = *(const float2*)(W_re + (size_t)n*DA + (tid<<2) + jc*2);
          float2 w_i = *(const float2*)(W_im + (size_t)n*DA + (tid<<2) + jc*2);
          #pragma unroll
          for (int q = 0; q < 8; q++){
            float mr = Msh_re[s][n][mc*8+q];   // broadcast LDS read, consumed immediately
            float mi = Msh_im[s][n][mc*8+q];
            cr0[q] += mr*w_r.x + mi*w_i.x;  ci0[q] += mr*w_i.x - mi*w_r.x;  // conj(M)*W
            cr1[q] += mr*w_r.y + mi*w_i.y;  ci1[q] += mr*w_i.y - mi*w_r.y;
          }
        }
        #pragma unroll
        for (int q = 0; q < 8; q++){
          nrm0 += cr0[q]*cr0[q] + ci0[q]*ci0[q];
          nrm1 += cr1[q]*cr1[q] + ci1[q]*ci1[q];
        }
      }
      md[s*JCOLS + jc*2 + 0] = 1.f/sqrtf(nrm0);
      md[s*JCOLS + jc*2 + 1] = 1.f/sqrtf(nrm1);
    }
  }

  // ---- phase 2: 20 greedy iterations
  for (int it = 0; it < MAXIT; it++){
    // A: rn2 (tid<4), t = M.residual (tid 64..319), any_act=0 (tid 448)
    if (tid < SPB){
      float e = 0.f;
      for (int m = 0; m < MM; m++){
        float rr = rsd_re[tid][m], ri = rsd_im[tid][m];
        e += rr*rr + ri*ri;
      }
      rn2_sh[tid] = e;
    } else if (tid >= 64 && tid < 320){
      int q = tid - 64, s = q >> 6, n = q & 63;
      float tr = 0.f, ti = 0.f;
      #pragma unroll
      for (int m = 0; m < MM; m++){
        float mr = Msh_re[s][n][m], mi = Msh_im[s][n][m];
        float rr = rsd_re[s][m], ri = rsd_im[s][m];
        tr += mr*rr - mi*ri;          // t[n] = sum_m M[n,m]*r[m]
        ti += mr*ri + mi*rr;
      }
      tsh[n][2*s]   = tr;
      tsh[n][2*s+1] = ti;
    } else if (tid == 448){
      any_act = 0;
    }
    __syncthreads();
    if (tid < SPB){
      int a = (actsh[tid] && (rn2_sh[tid] >= thr_sh[tid])) ? 1 : 0;
      actsh[tid] = a;
      if (a) any_act = 1;
    }

    // B: g[s][j] = sum_n conj(W[n,a])*t[s,n], a = tid*4+j  (no staging arrays)
    float gr[SPB][JCOLS], gi[SPB][JCOLS];
    #pragma unroll
    for (int s = 0; s < SPB; s++)
      #pragma unroll
      for (int j = 0; j < JCOLS; j++){ gr[s][j]=0.f; gi[s][j]=0.f; }
    for (int n = 0; n < NANT; n++){
      float4 t01 = *(const float4*)&tsh[n][0];   // t0r,t0i,t1r,t1i
      float4 t23 = *(const float4*)&tsh[n][4];   // t2r,t2i,t3r,t3i
      float4 wr = *(const float4*)(W_re + (size_t)n*DA + (tid<<2));
      float4 wi = *(const float4*)(W_im + (size_t)n*DA + (tid<<2));
      gr[0][0] += wr.x*t01.x + wi.x*t01.y;  gi[0][0] += wr.x*t01.y - wi.x*t01.x;
      gr[0][1] += wr.y*t01.x + wi.y*t01.y;  gi[0][1] += wr.y*t01.y - wi.y*t01.x;
      gr[0][2] += wr.z*t01.x + wi.z*t01.y;  gi[0][2] += wr.z*t01.y - wi.z*t01.x;
      gr[0][3] += wr.w*t01.x + wi.w*t01.y;  gi[0][3] += wr.w*t01.y - wi.w*t01.x;
      gr[1][0] += wr.x*t01.z + wi.x*t01.w;  gi[1][0] += wr.x*t01.w - wi.x*t01.z;
      gr[1][1] += wr.y*t01.z + wi.y*t01.w;  gi[1][1] += wr.y*t01.w - wi.y*t01.z;
      gr[1][2] += wr.z*t01.z + wi.z*t01.w;  gi[1][2] += wr.z*t01.w - wi.z*t01.z;
      gr[1][3] += wr.w*t01.z + wi.w*t01.w;  gi[1][3] += wr.w*t01.w - wi.w*t01.z;
      gr[2][0] += wr.x*t23.x + wi.x*t23.y;  gi[2][0] += wr.x*t23.y - wi.x*t23.x;
      gr[2][1] += wr.y*t23.x + wi.y*t23.y;  gi[2][1] += wr.y*t23.y - wi.y*t23.x;
      gr[2][2] += wr.z*t23.x + wi.z*t23.y;  gi[2][2] += wr.z*t23.y - wi.z*t23.x;
      gr[2][3] += wr.w*t23.x + wi.w*t23.y;  gi[2][3] += wr.w*t23.y - wi.w*t23.x;
      gr[3][0] += wr.x*t23.z + wi.x*t23.w;  gi[3][0] += wr.x*t23.w - wi.x*t23.z;
      gr[3][1] += wr.y*t23.z + wi.y*t23.w;  gi[3][1] += wr.y*t23.w - wi.y*t23.z;
      gr[3][2] += wr.z*t23.z + wi.z*t23.w;  gi[3][2] += wr.z*t23.w - wi.z*t23.z;
      gr[3][3] += wr.w*t23.z + wi.w*t23.w;  gi[3][3] += wr.w*t23.w - wi.w*t23.z;
    }

    // C: per-thread best (max c2, min idx on tie)
    float bc2[SPB]; int bix[SPB];
    #pragma unroll
    for (int s = 0; s < SPB; s++){ bc2[s] = -1.f; bix[s] = 0; }
    #pragma unroll
    for (int j = 0; j < JCOLS; j++){
      int a = (tid<<2) + j;
      #pragma unroll
      for (int s = 0; s < SPB; s++){
        float mdv = md[s*JCOLS + j];
        float cre = gr[s][j]*mdv, cim = gi[s][j]*mdv;
        float c2 = cre*cre + cim*cim;
        if (c2 > bc2[s]){ bc2[s] = c2; bix[s] = a; }
      }
    }
    #pragma unroll
    for (int off = 32; off; off >>= 1){
      #pragma unroll
      for (int s = 0; s < SPB; s++){
        float oc2 = __shfl_down(bc2[s], off);
        int   oix = __shfl_down(bix[s], off);
        if (oc2 > bc2[s] || (oc2 == bc2[s] && oix < bix[s])){ bc2[s]=oc2; bix[s]=oix; }
      }
    }
    if ((tid & 63) == 0){
      int wid = tid >> 6;
      #pragma unroll
      for (int s = 0; s < SPB; s++){ red_c2[wid][s]=bc2[s]; red_ix[wid][s]=bix[s]; }
    }
    __syncthreads();
    if (!any_act) break;                 // uniform across block

    if (tid < SPB){
      float bc = red_c2[0][tid]; int bi = red_ix[0][tid];
      #pragma unroll
      for (int w = 1; w < 16; w++){
        float c = red_c2[w][tid]; int i2 = red_ix[w][tid];
        if (c > bc || (c == bc && i2 < bi)){ bc=c; bi=i2; }
      }
      sel_ix[tid] = bi;
    }
    __syncthreads();

    // D: owning thread publishes selected value (static g/md indexing)
    #pragma unroll
    for (int s = 0; s < SPB; s++){
      int I = sel_ix[s];
      if ((I >> 2) == tid){
        int jj = I & 3;
        #pragma unroll
        for (int j = 0; j < JCOLS; j++){
          if (jj == j){
            float mdv = md[s*JCOLS + j];
            sel_vr[s] = gr[s][j]*mdv;
            sel_vi[s] = gi[s][j]*mdv;
            sel_md[s] = mdv;
          }
        }
      }
    }
    __syncthreads();

    // E: updates, gated per-sample
    if (tid < 64){
      int s = tid >> 4, m = tid & 15;
      if (actsh[s]){
        int I = sel_ix[s];
        float vr = sel_vr[s], vi = sel_vi[s], mdv = sel_md[s];
        float cre = 0.f, cim = 0.f;
        for (int n = 0; n < NANT; n++){
          float mr = Msh_re[s][n][m], mi = Msh_im[s][n][m];
          float wr = W_re[(size_t)n*DA + I], wi = W_im[(size_t)n*DA + I];
          cre += mr*wr + mi*wi;        // conj(M)*W
          cim += mr*wi - mi*wr;
        }
        cre *= mdv; cim *= mdv;
        rsd_re[s][m] -= vr*cre - vi*cim;
        rsd_im[s][m] -= vr*cim + vi*cre;
      }
    } else if (tid >= 64 && tid < 320){
      int q = tid - 64, s = q >> 6, n = q & 63;
      if (actsh[s]){
        int I = sel_ix[s];
        float vr = sel_vr[s], vi = sel_vi[s];
        float wr = W_re[(size_t)n*DA + I], wi = W_im[(size_t)n*DA + I];
        float ei = einv_sh[I];
        float er = wr*ei, em = wi*ei;  // E[:,I]
        resh_re[s][n] -= vr*er - vi*em;
        resh_im[s][n] -= vr*em + vi*er;
      }
    }
    __syncthreads();
  }

  // ---- epilogue: f32, six planes: re parts first (res, xhat, xhm), then im parts
  if (tid < 64){
    int s = tid >> 4, m = tid & 15; int b = b0 + s;
    float rr = rsd_re[s][m], ri = rsd_im[s][m];
    size_t base = (size_t)b*MM + m;                 // 0..16383
    if (base < outn)          out[base]          = rr;                        // res.re
    if (16384 + base < outn)  out[16384 + base]  = x_re[b*MM+m] - rr;         // xhat.re
    if (98304 + base < outn)  out[98304 + base]  = ri;                        // res.im
    if (114688 + base < outn) out[114688 + base] = x_im[b*MM+m] - ri;         // xhat.im
  } else if (tid >= 64 && tid < 320){
    int q = tid - 64, s = q >> 6, n = q & 63; int b = b0 + s;
    size_t base = (size_t)b*NANT + n;               // 0..65535
    if (32768 + base < outn)  out[32768 + base]  = xm_re[b*NANT+n] - resh_re[s][n];  // xhm.re
    if (131072 + base < outn) out[131072 + base] = xm_im[b*NANT+n] - resh_im[s][n];  // xhm.im
  }
}

extern "C" void kernel_launch(void* const* d_in, const int* in_sizes, int n_in,
                              void* d_out, int out_size, void* d_ws, size_t ws_size,
                              hipStream_t stream) {
  (void)in_sizes; (void)n_in; (void)d_ws; (void)ws_size;
  const float* x_re  = (const float*)d_in[0];
  const float* x_im  = (const float*)d_in[1];
  const float* xm_re = (const float*)d_in[2];
  const float* xm_im = (const float*)d_in[3];
  const float* M_re  = (const float*)d_in[4];
  const float* M_im  = (const float*)d_in[5];
  const float* W_re  = (const float*)d_in[6];
  const float* W_im  = (const float*)d_in[7];
  const float* sig   = (const float*)d_in[8];
  float* out = (float*)d_out;

  dim3 grid(NB_TOT / SPB), block(NTHR);
  hipLaunchKernelGGL(mpnet_kernel, grid, block, 0, stream,
                     x_re, x_im, xm_re, xm_im, M_re, M_im, W_re, W_im,
                     sig, out, out_size);
}

// Round 15
// 1677.714 us; speedup vs baseline: 1.2298x; 1.2298x over previous
//
#include <hip/hip_runtime.h>
#include <cstdint>
#include <cstddef>

#define NB_TOT 1024
#define NANT 64
#define MM 16
#define MPAD 17   // odd stride: strided LDS reads conflict-free
#define DA 4096
#define MAXIT 20
#define SPB 4     // samples per block
#define NTHR 1024 // 16 waves
#define JCOLS 4   // consecutive cols per thread: a = tid*4 + j
#define L_CONST 10.0f

__global__ __launch_bounds__(NTHR, 4)
void mpnet_kernel(const float* __restrict__ x_re, const float* __restrict__ x_im,
                  const float* __restrict__ xm_re, const float* __restrict__ xm_im,
                  const float* __restrict__ M_re, const float* __restrict__ M_im,
                  const float* __restrict__ W_re, const float* __restrict__ W_im,
                  const float* __restrict__ sigma,
                  float* __restrict__ out, int outn_i)
{
  __shared__ float Msh_re[SPB][NANT][MPAD];    // 17.4 KB
  __shared__ float Msh_im[SPB][NANT][MPAD];    // 17.4 KB
  __shared__ float md_lds[SPB][NTHR][JCOLS];   // 64 KB — md out of registers (kills spills)
  __shared__ float tsh[NANT][8];               // 2 KB
  __shared__ float einv_sh[DA];                // 16 KB
  __shared__ float rsd_re[SPB][MM], rsd_im[SPB][MM];
  __shared__ float resh_re[SPB][NANT], resh_im[SPB][NANT];
  __shared__ float red_c2[16][SPB];
  __shared__ int   red_ix[16][SPB];
  __shared__ int   sel_ix[SPB];
  __shared__ float sel_vr[SPB], sel_vi[SPB], sel_md[SPB];
  __shared__ float rn2_sh[SPB], thr_sh[SPB];
  __shared__ int   actsh[SPB];
  __shared__ int   any_act;

  const int tid = threadIdx.x;
  const int b0 = blockIdx.x * SPB;
  const size_t outn = (size_t)outn_i;

  // ---- init: stage M, residual(=x), res(=xm), thresholds
  for (int k2 = 0; k2 < 4; k2++){
    int idx = k2*NTHR + tid;            // 0..4095 = 4 samples x 64 n x 16 m
    int s = idx >> 10, rem = idx & 1023;
    int n = rem >> 4, m = rem & 15;
    Msh_re[s][n][m] = M_re[(size_t)b0*1024 + idx];
    Msh_im[s][n][m] = M_im[(size_t)b0*1024 + idx];
  }
  if (tid < SPB*MM){
    int s = tid >> 4, m = tid & 15;
    rsd_re[s][m] = x_re[(b0+s)*MM + m];
    rsd_im[s][m] = x_im[(b0+s)*MM + m];
  } else if (tid >= 64 && tid < 64 + SPB*NANT){
    int q = tid - 64, s = q >> 6, n = q & 63;
    resh_re[s][n] = xm_re[(b0+s)*NANT + n];
    resh_im[s][n] = xm_im[(b0+s)*NANT + n];
  } else if (tid >= 448 && tid < 448 + SPB){
    int s = tid - 448;
    float sg = sigma[b0+s];
    thr_sh[s] = ((sg*sg) * (float)NANT) * L_CONST;
    actsh[s] = 1;
  }

  // ---- phase 0: E column inverse norms (thread owns cols tid*4..+3)
  {
    float w2x=0.f, w2y=0.f, w2z=0.f, w2w=0.f;
    for (int n = 0; n < NANT; n++){
      float4 wr = *(const float4*)(W_re + (size_t)n*DA + (tid<<2));
      float4 wi = *(const float4*)(W_im + (size_t)n*DA + (tid<<2));
      w2x += wr.x*wr.x + wi.x*wi.x;
      w2y += wr.y*wr.y + wi.y*wi.y;
      w2z += wr.z*wr.z + wi.z*wi.z;
      w2w += wr.w*wr.w + wi.w*wi.w;
    }
    einv_sh[(tid<<2)+0] = 1.f/sqrtf(w2x);
    einv_sh[(tid<<2)+1] = 1.f/sqrtf(w2y);
    einv_sh[(tid<<2)+2] = 1.f/sqrtf(w2z);
    einv_sh[(tid<<2)+3] = 1.f/sqrtf(w2w);
  }
  __syncthreads();

  // ---- phase 1: md = 1/||M_D col||; j split in 2 passes of 2 cols; result -> LDS
  #pragma unroll
  for (int s = 0; s < SPB; s++){
    #pragma unroll
    for (int jc = 0; jc < 2; jc++){     // cols a = tid*4 + jc*2 + {0,1}
      float nrm0 = 0.f, nrm1 = 0.f;
      #pragma unroll
      for (int mc = 0; mc < 2; mc++){
        float cr0[8], ci0[8], cr1[8], ci1[8];
        #pragma unroll
        for (int q = 0; q < 8; q++){ cr0[q]=0.f; ci0[q]=0.f; cr1[q]=0.f; ci1[q]=0.f; }
        for (int n = 0; n < NANT; n++){
          float2 w_r = *(const float2*)(W_re + (size_t)n*DA + (tid<<2) + jc*2);
          float2 w_i = *(const float2*)(W_im + (size_t)n*DA + (tid<<2) + jc*2);
          #pragma unroll
          for (int q = 0; q < 8; q++){
            float mr = Msh_re[s][n][mc*8+q];   // broadcast LDS read
            float mi = Msh_im[s][n][mc*8+q];
            cr0[q] += mr*w_r.x + mi*w_i.x;  ci0[q] += mr*w_i.x - mi*w_r.x;  // conj(M)*W
            cr1[q] += mr*w_r.y + mi*w_i.y;  ci1[q] += mr*w_i.y - mi*w_r.y;
          }
        }
        #pragma unroll
        for (int q = 0; q < 8; q++){
          nrm0 += cr0[q]*cr0[q] + ci0[q]*ci0[q];
          nrm1 += cr1[q]*cr1[q] + ci1[q]*ci1[q];
        }
      }
      md_lds[s][tid][jc*2+0] = 1.f/sqrtf(nrm0);
      md_lds[s][tid][jc*2+1] = 1.f/sqrtf(nrm1);
    }
  }

  // ---- phase 2: 20 greedy iterations
  for (int it = 0; it < MAXIT; it++){
    // A: rn2 (tid<4), t = M.residual (tid 64..319), any_act=0 (tid 448)
    if (tid < SPB){
      float e = 0.f;
      for (int m = 0; m < MM; m++){
        float rr = rsd_re[tid][m], ri = rsd_im[tid][m];
        e += rr*rr + ri*ri;
      }
      rn2_sh[tid] = e;
    } else if (tid >= 64 && tid < 320){
      int q = tid - 64, s = q >> 6, n = q & 63;
      float tr = 0.f, ti = 0.f;
      #pragma unroll
      for (int m = 0; m < MM; m++){
        float mr = Msh_re[s][n][m], mi = Msh_im[s][n][m];
        float rr = rsd_re[s][m], ri = rsd_im[s][m];
        tr += mr*rr - mi*ri;          // t[n] = sum_m M[n,m]*r[m]
        ti += mr*ri + mi*rr;
      }
      tsh[n][2*s]   = tr;
      tsh[n][2*s+1] = ti;
    } else if (tid == 448){
      any_act = 0;
    }
    __syncthreads();
    if (tid < SPB){
      int a = (actsh[tid] && (rn2_sh[tid] >= thr_sh[tid])) ? 1 : 0;
      actsh[tid] = a;
      if (a) any_act = 1;
    }

    // B: g[s][j] = sum_n conj(W[n,a])*t[s,n], a = tid*4+j
    float gr[SPB][JCOLS], gi[SPB][JCOLS];
    #pragma unroll
    for (int s = 0; s < SPB; s++)
      #pragma unroll
      for (int j = 0; j < JCOLS; j++){ gr[s][j]=0.f; gi[s][j]=0.f; }
    for (int n = 0; n < NANT; n++){
      float4 t01 = *(const float4*)&tsh[n][0];
      float4 t23 = *(const float4*)&tsh[n][4];
      float4 wr = *(const float4*)(W_re + (size_t)n*DA + (tid<<2));
      float4 wi = *(const float4*)(W_im + (size_t)n*DA + (tid<<2));
      gr[0][0] += wr.x*t01.x + wi.x*t01.y;  gi[0][0] += wr.x*t01.y - wi.x*t01.x;
      gr[0][1] += wr.y*t01.x + wi.y*t01.y;  gi[0][1] += wr.y*t01.y - wi.y*t01.x;
      gr[0][2] += wr.z*t01.x + wi.z*t01.y;  gi[0][2] += wr.z*t01.y - wi.z*t01.x;
      gr[0][3] += wr.w*t01.x + wi.w*t01.y;  gi[0][3] += wr.w*t01.y - wi.w*t01.x;
      gr[1][0] += wr.x*t01.z + wi.x*t01.w;  gi[1][0] += wr.x*t01.w - wi.x*t01.z;
      gr[1][1] += wr.y*t01.z + wi.y*t01.w;  gi[1][1] += wr.y*t01.w - wi.y*t01.z;
      gr[1][2] += wr.z*t01.z + wi.z*t01.w;  gi[1][2] += wr.z*t01.w - wi.z*t01.z;
      gr[1][3] += wr.w*t01.z + wi.w*t01.w;  gi[1][3] += wr.w*t01.w - wi.w*t01.z;
      gr[2][0] += wr.x*t23.x + wi.x*t23.y;  gi[2][0] += wr.x*t23.y - wi.x*t23.x;
      gr[2][1] += wr.y*t23.x + wi.y*t23.y;  gi[2][1] += wr.y*t23.y - wi.y*t23.x;
      gr[2][2] += wr.z*t23.x + wi.z*t23.y;  gi[2][2] += wr.z*t23.y - wi.z*t23.x;
      gr[2][3] += wr.w*t23.x + wi.w*t23.y;  gi[2][3] += wr.w*t23.y - wi.w*t23.x;
      gr[3][0] += wr.x*t23.z + wi.x*t23.w;  gi[3][0] += wr.x*t23.w - wi.x*t23.z;
      gr[3][1] += wr.y*t23.z + wi.y*t23.w;  gi[3][1] += wr.y*t23.w - wi.y*t23.z;
      gr[3][2] += wr.z*t23.z + wi.z*t23.w;  gi[3][2] += wr.z*t23.w - wi.z*t23.z;
      gr[3][3] += wr.w*t23.z + wi.w*t23.w;  gi[3][3] += wr.w*t23.w - wi.w*t23.z;
    }

    // C: per-thread best (md from LDS); gr/gi DEAD after this block
    float bc2[SPB]; int bix[SPB];
    #pragma unroll
    for (int s = 0; s < SPB; s++){
      float4 mdv4 = *(const float4*)&md_lds[s][tid][0];
      float m0 = mdv4.x, m1 = mdv4.y, m2 = mdv4.z, m3 = mdv4.w;
      float c0 = (gr[s][0]*gr[s][0] + gi[s][0]*gi[s][0]) * (m0*m0);
      float c1 = (gr[s][1]*gr[s][1] + gi[s][1]*gi[s][1]) * (m1*m1);
      float c2v = (gr[s][2]*gr[s][2] + gi[s][2]*gi[s][2]) * (m2*m2);
      float c3 = (gr[s][3]*gr[s][3] + gi[s][3]*gi[s][3]) * (m3*m3);
      float bc = c0; int bi = (tid<<2);
      if (c1 > bc){ bc = c1; bi = (tid<<2)+1; }
      if (c2v > bc){ bc = c2v; bi = (tid<<2)+2; }
      if (c3 > bc){ bc = c3; bi = (tid<<2)+3; }
      bc2[s] = bc; bix[s] = bi;
    }
    #pragma unroll
    for (int off = 32; off; off >>= 1){
      #pragma unroll
      for (int s = 0; s < SPB; s++){
        float oc2 = __shfl_down(bc2[s], off);
        int   oix = __shfl_down(bix[s], off);
        if (oc2 > bc2[s] || (oc2 == bc2[s] && oix < bix[s])){ bc2[s]=oc2; bix[s]=oix; }
      }
    }
    if ((tid & 63) == 0){
      int wid = tid >> 6;
      #pragma unroll
      for (int s = 0; s < SPB; s++){ red_c2[wid][s]=bc2[s]; red_ix[wid][s]=bix[s]; }
    }
    __syncthreads();
    if (!any_act) break;                 // uniform across block

    // D: 4 waves: cross-wave argmax + recompute selected value (gr/gi not needed)
    if (tid < 256){
      int s = tid >> 6, lane = tid & 63;
      float c = (lane < 16) ? red_c2[lane][s] : -1.f;
      int   bi = (lane < 16) ? red_ix[lane][s] : 0x7FFFFFFF;
      #pragma unroll
      for (int off = 8; off; off >>= 1){
        float oc = __shfl_down(c, off);
        int   oi = __shfl_down(bi, off);
        if (oc > c || (oc == c && oi < bi)){ c = oc; bi = oi; }
      }
      int I = __shfl(bi, 0);
      // val = sum_n conj(W[n,I]) * t[s,n]; lane = n
      float wr = W_re[(size_t)lane*DA + I], wi = W_im[(size_t)lane*DA + I];
      float tr = tsh[lane][2*s], ti = tsh[lane][2*s+1];
      float vr = wr*tr + wi*ti;
      float vi = wr*ti - wi*tr;
      #pragma unroll
      for (int off = 32; off; off >>= 1){
        vr += __shfl_down(vr, off);
        vi += __shfl_down(vi, off);
      }
      if (lane == 0){
        float mdv = md_lds[s][I>>2][I&3];
        sel_ix[s] = I;
        sel_vr[s] = vr*mdv;
        sel_vi[s] = vi*mdv;
        sel_md[s] = mdv;
      }
    }
    __syncthreads();

    // E: updates, gated per-sample
    if (tid < 64){
      int s = tid >> 4, m = tid & 15;
      if (actsh[s]){
        int I = sel_ix[s];
        float vr = sel_vr[s], vi = sel_vi[s], mdv = sel_md[s];
        float cre = 0.f, cim = 0.f;
        for (int n = 0; n < NANT; n++){
          float mr = Msh_re[s][n][m], mi = Msh_im[s][n][m];
          float wr = W_re[(size_t)n*DA + I], wi = W_im[(size_t)n*DA + I];
          cre += mr*wr + mi*wi;        // conj(M)*W
          cim += mr*wi - mi*wr;
        }
        cre *= mdv; cim *= mdv;
        rsd_re[s][m] -= vr*cre - vi*cim;
        rsd_im[s][m] -= vr*cim + vi*cre;
      }
    } else if (tid >= 64 && tid < 320){
      int q = tid - 64, s = q >> 6, n = q & 63;
      if (actsh[s]){
        int I = sel_ix[s];
        float vr = sel_vr[s], vi = sel_vi[s];
        float wr = W_re[(size_t)n*DA + I], wi = W_im[(size_t)n*DA + I];
        float ei = einv_sh[I];
        float er = wr*ei, em = wi*ei;  // E[:,I]
        resh_re[s][n] -= vr*er - vi*em;
        resh_im[s][n] -= vr*em + vi*er;
      }
    }
    __syncthreads();
  }

  // ---- epilogue: f32, six planes: re parts first (res, xhat, xhm), then im parts
  if (tid < 64){
    int s = tid >> 4, m = tid & 15; int b = b0 + s;
    float rr = rsd_re[s][m], ri = rsd_im[s][m];
    size_t base = (size_t)b*MM + m;                 // 0..16383
    if (base < outn)          out[base]          = rr;                        // res.re
    if (16384 + base < outn)  out[16384 + base]  = x_re[b*MM+m] - rr;         // xhat.re
    if (98304 + base < outn)  out[98304 + base]  = ri;                        // res.im
    if (114688 + base < outn) out[114688 + base] = x_im[b*MM+m] - ri;         // xhat.im
  } else if (tid >= 64 && tid < 320){
    int q = tid - 64, s = q >> 6, n = q & 63; int b = b0 + s;
    size_t base = (size_t)b*NANT + n;               // 0..65535
    if (32768 + base < outn)  out[32768 + base]  = xm_re[b*NANT+n] - resh_re[s][n];  // xhm.re
    if (131072 + base < outn) out[131072 + base] = xm_im[b*NANT+n] - resh_im[s][n];  // xhm.im
  }
}

extern "C" void kernel_launch(void* const* d_in, const int* in_sizes, int n_in,
                              void* d_out, int out_size, void* d_ws, size_t ws_size,
                              hipStream_t stream) {
  (void)in_sizes; (void)n_in; (void)d_ws; (void)ws_size;
  const float* x_re  = (const float*)d_in[0];
  const float* x_im  = (const float*)d_in[1];
  const float* xm_re = (const float*)d_in[2];
  const float* xm_im = (const float*)d_in[3];
  const float* M_re  = (const float*)d_in[4];
  const float* M_im  = (const float*)d_in[5];
  const float* W_re  = (const float*)d_in[6];
  const float* W_im  = (const float*)d_in[7];
  const float* sig   = (const float*)d_in[8];
  float* out = (float*)d_out;

  dim3 grid(NB_TOT / SPB), block(NTHR);
  hipLaunchKernelGGL(mpnet_kernel, grid, block, 0, stream,
                     x_re, x_im, xm_re, xm_im, M_re, M_im, W_re, W_im,
                     sig, out, out_size);
}

// Round 16
// 1588.541 us; speedup vs baseline: 1.2989x; 1.0561x over previous
//
#include <hip/hip_runtime.h>
#include <cstdint>
#include <cstddef>

#define NB_TOT 1024
#define NANT 64
#define MM 16
#define MPAD 20   // float2/float4-aligned rows for vector LDS reads
#define DA 4096
#define MAXIT 20
#define SPB 4     // samples per block
#define NTHR 1024 // 16 waves
#define JCOLS 4   // consecutive cols per thread: a = tid*4 + j
#define L_CONST 10.0f

__global__ __launch_bounds__(NTHR, 4)
void mpnet_kernel(const float* __restrict__ x_re, const float* __restrict__ x_im,
                  const float* __restrict__ xm_re, const float* __restrict__ xm_im,
                  const float* __restrict__ M_re, const float* __restrict__ M_im,
                  const float* __restrict__ W_re, const float* __restrict__ W_im,
                  const float* __restrict__ sigma,
                  float* __restrict__ out, int outn_i)
{
  __shared__ float Msh_re[SPB][NANT][MPAD];    // 20 KB
  __shared__ float Msh_im[SPB][NANT][MPAD];    // 20 KB
  __shared__ float md_T[SPB][JCOLS][NTHR];     // 64 KB, transposed: lane-stride-4B reads
  __shared__ float tsh[NANT][8];               // 2 KB
  __shared__ float rsd_re[SPB][MM], rsd_im[SPB][MM];
  __shared__ float resh_re[SPB][NANT], resh_im[SPB][NANT];
  __shared__ float red_c2[16][SPB];
  __shared__ int   red_ix[16][SPB];
  __shared__ int   sel_ix[SPB];
  __shared__ float sel_vr[SPB], sel_vi[SPB], sel_md[SPB], sel_ei[SPB];
  __shared__ float rn2_sh[SPB], thr_sh[SPB];
  __shared__ int   actsh[SPB];

  const int tid = threadIdx.x;
  const int b0 = blockIdx.x * SPB;
  const size_t outn = (size_t)outn_i;

  // ---- init: stage M, residual(=x), res(=xm), thresholds
  for (int k2 = 0; k2 < 4; k2++){
    int idx = k2*NTHR + tid;            // 0..4095 = 4 samples x 64 n x 16 m
    int s = idx >> 10, rem = idx & 1023;
    int n = rem >> 4, m = rem & 15;
    Msh_re[s][n][m] = M_re[(size_t)b0*1024 + idx];
    Msh_im[s][n][m] = M_im[(size_t)b0*1024 + idx];
  }
  if (tid < SPB*MM){
    int s = tid >> 4, m = tid & 15;
    rsd_re[s][m] = x_re[(b0+s)*MM + m];
    rsd_im[s][m] = x_im[(b0+s)*MM + m];
  } else if (tid >= 64 && tid < 64 + SPB*NANT){
    int q = tid - 64, s = q >> 6, n = q & 63;
    resh_re[s][n] = xm_re[(b0+s)*NANT + n];
    resh_im[s][n] = xm_im[(b0+s)*NANT + n];
  } else if (tid >= 448 && tid < 448 + SPB){
    int s = tid - 448;
    float sg = sigma[b0+s];
    thr_sh[s] = ((sg*sg) * (float)NANT) * L_CONST;
    actsh[s] = 1;
  }
  __syncthreads();

  // ---- phase 1: md = 1/||M_D col||; j in 2 passes of 2 cols; float2 LDS reads; -> md_T
  #pragma unroll
  for (int s = 0; s < SPB; s++){
    #pragma unroll
    for (int jc = 0; jc < 2; jc++){     // cols a = tid*4 + jc*2 + {0,1}
      float nrm0 = 0.f, nrm1 = 0.f;
      #pragma unroll
      for (int mc = 0; mc < 2; mc++){
        float cr0[8], ci0[8], cr1[8], ci1[8];
        #pragma unroll
        for (int q = 0; q < 8; q++){ cr0[q]=0.f; ci0[q]=0.f; cr1[q]=0.f; ci1[q]=0.f; }
        #pragma unroll 2
        for (int n = 0; n < NANT; n++){
          float2 w_r = *(const float2*)(W_re + (size_t)n*DA + (tid<<2) + jc*2);
          float2 w_i = *(const float2*)(W_im + (size_t)n*DA + (tid<<2) + jc*2);
          #pragma unroll
          for (int q2 = 0; q2 < 4; q2++){
            float2 mr = *(const float2*)&Msh_re[s][n][mc*8 + q2*2];   // broadcast b64
            float2 mi = *(const float2*)&Msh_im[s][n][mc*8 + q2*2];
            cr0[q2*2+0] += mr.x*w_r.x + mi.x*w_i.x;  ci0[q2*2+0] += mr.x*w_i.x - mi.x*w_r.x;
            cr0[q2*2+1] += mr.y*w_r.x + mi.y*w_i.x;  ci0[q2*2+1] += mr.y*w_i.x - mi.y*w_r.x;
            cr1[q2*2+0] += mr.x*w_r.y + mi.x*w_i.y;  ci1[q2*2+0] += mr.x*w_i.y - mi.x*w_r.y;
            cr1[q2*2+1] += mr.y*w_r.y + mi.y*w_i.y;  ci1[q2*2+1] += mr.y*w_i.y - mi.y*w_r.y;
          }
        }
        #pragma unroll
        for (int q = 0; q < 8; q++){
          nrm0 += cr0[q]*cr0[q] + ci0[q]*ci0[q];
          nrm1 += cr1[q]*cr1[q] + ci1[q]*ci1[q];
        }
      }
      md_T[s][jc*2+0][tid] = 1.f/sqrtf(nrm0);
      md_T[s][jc*2+1][tid] = 1.f/sqrtf(nrm1);
    }
  }
  // (no barrier needed: phase C reads own-thread md_T; phase D reads after barriers)

  // ---- phase 2: greedy iterations with per-sample active gating
  for (int it = 0; it < MAXIT; it++){
    // A: rn2 (tid<4), t = M.residual for still-active samples (tid 64..319)
    if (tid < SPB){
      float e = 0.f;
      for (int m = 0; m < MM; m++){
        float rr = rsd_re[tid][m], ri = rsd_im[tid][m];
        e += rr*rr + ri*ri;
      }
      rn2_sh[tid] = e;
    } else if (tid >= 64 && tid < 320){
      int q = tid - 64, s = q >> 6, n = q & 63;
      if (actsh[s]){                      // uniform per wave
        float tr = 0.f, ti = 0.f;
        #pragma unroll
        for (int m = 0; m < MM; m++){
          float mr = Msh_re[s][n][m], mi = Msh_im[s][n][m];
          float rr = rsd_re[s][m], ri = rsd_im[s][m];
          tr += mr*rr - mi*ri;            // t[n] = sum_m M[n,m]*r[m]
          ti += mr*ri + mi*rr;
        }
        tsh[n][2*s]   = tr;
        tsh[n][2*s+1] = ti;
      }
    }
    __syncthreads();

    // uniform per-sample active mask (benign race on actsh: rewrite is idempotent)
    bool a0 = actsh[0] && (rn2_sh[0] >= thr_sh[0]);
    bool a1 = actsh[1] && (rn2_sh[1] >= thr_sh[1]);
    bool a2 = actsh[2] && (rn2_sh[2] >= thr_sh[2]);
    bool a3 = actsh[3] && (rn2_sh[3] >= thr_sh[3]);
    if (tid < 4){
      int v = (tid==0) ? (int)a0 : (tid==1) ? (int)a1 : (tid==2) ? (int)a2 : (int)a3;
      actsh[tid] = v;
    }
    if (!(a0 || a1 || a2 || a3)) break;   // uniform: break BEFORE doing B work

    // B: g[s][j] = sum_n conj(W[n,a])*t[s,n], a = tid*4+j ; gated per sample
    float gr[SPB][JCOLS], gi[SPB][JCOLS];
    #pragma unroll
    for (int s = 0; s < SPB; s++)
      #pragma unroll
      for (int j = 0; j < JCOLS; j++){ gr[s][j]=0.f; gi[s][j]=0.f; }
    #pragma unroll 4
    for (int n = 0; n < NANT; n++){
      float4 t01 = *(const float4*)&tsh[n][0];
      float4 t23 = *(const float4*)&tsh[n][4];
      float4 wr = *(const float4*)(W_re + (size_t)n*DA + (tid<<2));
      float4 wi = *(const float4*)(W_im + (size_t)n*DA + (tid<<2));
      if (a0){
        gr[0][0] += wr.x*t01.x + wi.x*t01.y;  gi[0][0] += wr.x*t01.y - wi.x*t01.x;
        gr[0][1] += wr.y*t01.x + wi.y*t01.y;  gi[0][1] += wr.y*t01.y - wi.y*t01.x;
        gr[0][2] += wr.z*t01.x + wi.z*t01.y;  gi[0][2] += wr.z*t01.y - wi.z*t01.x;
        gr[0][3] += wr.w*t01.x + wi.w*t01.y;  gi[0][3] += wr.w*t01.y - wi.w*t01.x;
      }
      if (a1){
        gr[1][0] += wr.x*t01.z + wi.x*t01.w;  gi[1][0] += wr.x*t01.w - wi.x*t01.z;
        gr[1][1] += wr.y*t01.z + wi.y*t01.w;  gi[1][1] += wr.y*t01.w - wi.y*t01.z;
        gr[1][2] += wr.z*t01.z + wi.z*t01.w;  gi[1][2] += wr.z*t01.w - wi.z*t01.z;
        gr[1][3] += wr.w*t01.z + wi.w*t01.w;  gi[1][3] += wr.w*t01.w - wi.w*t01.z;
      }
      if (a2){
        gr[2][0] += wr.x*t23.x + wi.x*t23.y;  gi[2][0] += wr.x*t23.y - wi.x*t23.x;
        gr[2][1] += wr.y*t23.x + wi.y*t23.y;  gi[2][1] += wr.y*t23.y - wi.y*t23.x;
        gr[2][2] += wr.z*t23.x + wi.z*t23.y;  gi[2][2] += wr.z*t23.y - wi.z*t23.x;
        gr[2][3] += wr.w*t23.x + wi.w*t23.y;  gi[2][3] += wr.w*t23.y - wi.w*t23.x;
      }
      if (a3){
        gr[3][0] += wr.x*t23.z + wi.x*t23.w;  gi[3][0] += wr.x*t23.w - wi.x*t23.z;
        gr[3][1] += wr.y*t23.z + wi.y*t23.w;  gi[3][1] += wr.y*t23.w - wi.y*t23.z;
        gr[3][2] += wr.z*t23.z + wi.z*t23.w;  gi[3][2] += wr.z*t23.w - wi.z*t23.z;
        gr[3][3] += wr.w*t23.z + wi.w*t23.w;  gi[3][3] += wr.w*t23.w - wi.w*t23.z;
      }
    }

    // C: per-thread best (md_T conflict-free), gated; then wave reduce
    const bool acts[4] = {a0, a1, a2, a3};
    float bc2[SPB]; int bix[SPB];
    #pragma unroll
    for (int s = 0; s < SPB; s++){
      bc2[s] = -1.f; bix[s] = 0;
      if (acts[s]){
        float m0 = md_T[s][0][tid], m1 = md_T[s][1][tid];
        float m2 = md_T[s][2][tid], m3 = md_T[s][3][tid];
        float c0 = (gr[s][0]*gr[s][0] + gi[s][0]*gi[s][0]) * (m0*m0);
        float c1 = (gr[s][1]*gr[s][1] + gi[s][1]*gi[s][1]) * (m1*m1);
        float c2v = (gr[s][2]*gr[s][2] + gi[s][2]*gi[s][2]) * (m2*m2);
        float c3 = (gr[s][3]*gr[s][3] + gi[s][3]*gi[s][3]) * (m3*m3);
        float bc = c0; int bi = (tid<<2);
        if (c1 > bc){ bc = c1; bi = (tid<<2)+1; }
        if (c2v > bc){ bc = c2v; bi = (tid<<2)+2; }
        if (c3 > bc){ bc = c3; bi = (tid<<2)+3; }
        bc2[s] = bc; bix[s] = bi;
      }
    }
    #pragma unroll
    for (int s = 0; s < SPB; s++){
      if (acts[s]){
        #pragma unroll
        for (int off = 32; off; off >>= 1){
          float oc2 = __shfl_down(bc2[s], off);
          int   oix = __shfl_down(bix[s], off);
          if (oc2 > bc2[s] || (oc2 == bc2[s] && oix < bix[s])){ bc2[s]=oc2; bix[s]=oix; }
        }
      }
    }
    if ((tid & 63) == 0){
      int wid = tid >> 6;
      #pragma unroll
      for (int s = 0; s < SPB; s++){
        if (acts[s]){ red_c2[wid][s]=bc2[s]; red_ix[wid][s]=bix[s]; }
      }
    }
    __syncthreads();

    // D: per active sample (one wave each): cross-wave argmax + recompute val + einv
    if (tid < 256){
      int s = tid >> 6, lane = tid & 63;
      if (actsh[s]){                      // uniform per wave
        float c = (lane < 16) ? red_c2[lane][s] : -1.f;
        int   bi = (lane < 16) ? red_ix[lane][s] : 0x7FFFFFFF;
        #pragma unroll
        for (int off = 8; off; off >>= 1){
          float oc = __shfl_down(c, off);
          int   oi = __shfl_down(bi, off);
          if (oc > c || (oc == c && oi < bi)){ c = oc; bi = oi; }
        }
        int I = __shfl(bi, 0);
        // val = sum_n conj(W[n,I]) * t[s,n]; E-col norm alongside; lane = n
        float wr = W_re[(size_t)lane*DA + I], wi = W_im[(size_t)lane*DA + I];
        float tr = tsh[lane][2*s], ti = tsh[lane][2*s+1];
        float vr = wr*tr + wi*ti;
        float vi = wr*ti - wi*tr;
        float w2 = wr*wr + wi*wi;
        #pragma unroll
        for (int off = 32; off; off >>= 1){
          vr += __shfl_down(vr, off);
          vi += __shfl_down(vi, off);
          w2 += __shfl_down(w2, off);
        }
        if (lane == 0){
          float mdv = md_T[s][I & 3][I >> 2];
          sel_ix[s] = I;
          sel_vr[s] = vr*mdv;
          sel_vi[s] = vi*mdv;
          sel_md[s] = mdv;
          sel_ei[s] = rsqrtf(w2);
        }
      }
    }
    __syncthreads();

    // E: updates, gated per-sample
    if (tid < 64){
      int s = tid >> 4, m = tid & 15;
      if (actsh[s]){
        int I = sel_ix[s];
        float vr = sel_vr[s], vi = sel_vi[s], mdv = sel_md[s];
        float cre = 0.f, cim = 0.f;
        for (int n = 0; n < NANT; n++){
          float mr = Msh_re[s][n][m], mi = Msh_im[s][n][m];
          float wr = W_re[(size_t)n*DA + I], wi = W_im[(size_t)n*DA + I];
          cre += mr*wr + mi*wi;           // conj(M)*W
          cim += mr*wi - mi*wr;
        }
        cre *= mdv; cim *= mdv;
        rsd_re[s][m] -= vr*cre - vi*cim;
        rsd_im[s][m] -= vr*cim + vi*cre;
      }
    } else if (tid >= 64 && tid < 320){
      int q = tid - 64, s = q >> 6, n = q & 63;
      if (actsh[s]){
        int I = sel_ix[s];
        float vr = sel_vr[s], vi = sel_vi[s];
        float wr = W_re[(size_t)n*DA + I], wi = W_im[(size_t)n*DA + I];
        float ei = sel_ei[s];
        float er = wr*ei, em = wi*ei;     // E[:,I]
        resh_re[s][n] -= vr*er - vi*em;
        resh_im[s][n] -= vr*em + vi*er;
      }
    }
    __syncthreads();
  }

  // ---- epilogue: f32, six planes: re parts first (res, xhat, xhm), then im parts
  if (tid < 64){
    int s = tid >> 4, m = tid & 15; int b = b0 + s;
    float rr = rsd_re[s][m], ri = rsd_im[s][m];
    size_t base = (size_t)b*MM + m;                 // 0..16383
    if (base < outn)          out[base]          = rr;                        // res.re
    if (16384 + base < outn)  out[16384 + base]  = x_re[b*MM+m] - rr;         // xhat.re
    if (98304 + base < outn)  out[98304 + base]  = ri;                        // res.im
    if (114688 + base < outn) out[114688 + base] = x_im[b*MM+m] - ri;         // xhat.im
  } else if (tid >= 64 && tid < 320){
    int q = tid - 64, s = q >> 6, n = q & 63; int b = b0 + s;
    size_t base = (size_t)b*NANT + n;               // 0..65535
    if (32768 + base < outn)  out[32768 + base]  = xm_re[b*NANT+n] - resh_re[s][n];  // xhm.re
    if (131072 + base < outn) out[131072 + base] = xm_im[b*NANT+n] - resh_im[s][n];  // xhm.im
  }
}

extern "C" void kernel_launch(void* const* d_in, const int* in_sizes, int n_in,
                              void* d_out, int out_size, void* d_ws, size_t ws_size,
                              hipStream_t stream) {
  (void)in_sizes; (void)n_in; (void)d_ws; (void)ws_size;
  const float* x_re  = (const float*)d_in[0];
  const float* x_im  = (const float*)d_in[1];
  const float* xm_re = (const float*)d_in[2];
  const float* xm_im = (const float*)d_in[3];
  const float* M_re  = (const float*)d_in[4];
  const float* M_im  = (const float*)d_in[5];
  const float* W_re  = (const float*)d_in[6];
  const float* W_im  = (const float*)d_in[7];
  const float* sig   = (const float*)d_in[8];
  float* out = (float*)d_out;

  dim3 grid(NB_TOT / SPB), block(NTHR);
  hipLaunchKernelGGL(mpnet_kernel, grid, block, 0, stream,
                     x_re, x_im, xm_re, xm_im, M_re, M_im, W_re, W_im,
                     sig, out, out_size);
}

// Round 17
// 1531.481 us; speedup vs baseline: 1.3473x; 1.0373x over previous
//
#include <hip/hip_runtime.h>
#include <cstdint>
#include <cstddef>

#define NB_TOT 1024
#define NANT 64
#define MM 16
#define MPAD 17   // odd stride: per-lane strided LDS reads are 2-way (free)
#define DA 4096
#define MAXIT 20
#define SPB 4     // samples per block
#define NTHR 1024 // 16 waves
#define JCOLS 4   // consecutive cols per thread: a = tid*4 + j
#define L_CONST 10.0f

__global__ __launch_bounds__(NTHR, 4)
void mpnet_kernel(const float* __restrict__ x_re, const float* __restrict__ x_im,
                  const float* __restrict__ xm_re, const float* __restrict__ xm_im,
                  const float* __restrict__ M_re, const float* __restrict__ M_im,
                  const float* __restrict__ W_re, const float* __restrict__ W_im,
                  const float* __restrict__ sigma,
                  float* __restrict__ out, int outn_i)
{
  __shared__ float Msh_re[SPB][NANT][MPAD];    // 17.4 KB (phases A/E only)
  __shared__ float Msh_im[SPB][NANT][MPAD];    // 17.4 KB
  __shared__ float md_T[SPB][JCOLS][NTHR];     // 64 KB, transposed (conflict-free)
  __shared__ float tsh[NANT][8];               // 2 KB
  __shared__ float rsd_re[SPB][MM], rsd_im[SPB][MM];
  __shared__ float resh_re[SPB][NANT], resh_im[SPB][NANT];
  __shared__ float red_c2[16][SPB];
  __shared__ int   red_ix[16][SPB];
  __shared__ int   sel_ix[SPB];
  __shared__ float sel_vr[SPB], sel_vi[SPB], sel_md[SPB], sel_ei[SPB];
  __shared__ float rn2_sh[SPB], thr_sh[SPB];
  __shared__ int   actsh[SPB];

  const int tid = threadIdx.x;
  const int b0 = blockIdx.x * SPB;
  const size_t outn = (size_t)outn_i;

  // ---- init: stage M (for A/E), residual(=x), res(=xm), thresholds
  for (int k2 = 0; k2 < 4; k2++){
    int idx = k2*NTHR + tid;            // 0..4095 = 4 samples x 64 n x 16 m
    int s = idx >> 10, rem = idx & 1023;
    int n = rem >> 4, m = rem & 15;
    Msh_re[s][n][m] = M_re[(size_t)b0*1024 + idx];
    Msh_im[s][n][m] = M_im[(size_t)b0*1024 + idx];
  }
  if (tid < SPB*MM){
    int s = tid >> 4, m = tid & 15;
    rsd_re[s][m] = x_re[(b0+s)*MM + m];
    rsd_im[s][m] = x_im[(b0+s)*MM + m];
  } else if (tid >= 64 && tid < 64 + SPB*NANT){
    int q = tid - 64, s = q >> 6, n = q & 63;
    resh_re[s][n] = xm_re[(b0+s)*NANT + n];
    resh_im[s][n] = xm_im[(b0+s)*NANT + n];
  } else if (tid >= 448 && tid < 448 + SPB){
    int s = tid - 448;
    float sg = sigma[b0+s];
    thr_sh[s] = ((sg*sg) * (float)NANT) * L_CONST;
    actsh[s] = 1;
  }
  // NO barrier yet: phase 1 reads M from GLOBAL (uniform addrs), not LDS.

  // ---- phase 1: md = 1/||M_D col||; M via uniform (scalar) global loads
  #pragma unroll
  for (int s = 0; s < SPB; s++){
    const float* MrS = M_re + (size_t)(b0+s)*1024;   // [n][m], uniform base
    const float* MiS = M_im + (size_t)(b0+s)*1024;
    #pragma unroll
    for (int jc = 0; jc < 2; jc++){     // cols a = tid*4 + jc*2 + {0,1}
      float nrm0 = 0.f, nrm1 = 0.f;
      #pragma unroll
      for (int mc = 0; mc < 2; mc++){
        float cr0[8], ci0[8], cr1[8], ci1[8];
        #pragma unroll
        for (int q = 0; q < 8; q++){ cr0[q]=0.f; ci0[q]=0.f; cr1[q]=0.f; ci1[q]=0.f; }
        #pragma unroll 4
        for (int n = 0; n < NANT; n++){
          float2 w_r = *(const float2*)(W_re + (size_t)n*DA + (tid<<2) + jc*2);
          float2 w_i = *(const float2*)(W_im + (size_t)n*DA + (tid<<2) + jc*2);
          const float* Mr = MrS + n*MM + mc*8;       // uniform across lanes
          const float* Mi = MiS + n*MM + mc*8;
          #pragma unroll
          for (int q = 0; q < 8; q++){
            float mr = Mr[q], mi = Mi[q];            // scalar (SMEM) loads
            cr0[q] += mr*w_r.x + mi*w_i.x;  ci0[q] += mr*w_i.x - mi*w_r.x;  // conj(M)*W
            cr1[q] += mr*w_r.y + mi*w_i.y;  ci1[q] += mr*w_i.y - mi*w_r.y;
          }
        }
        #pragma unroll
        for (int q = 0; q < 8; q++){
          nrm0 += cr0[q]*cr0[q] + ci0[q]*ci0[q];
          nrm1 += cr1[q]*cr1[q] + ci1[q]*ci1[q];
        }
      }
      md_T[s][jc*2+0][tid] = 1.f/sqrtf(nrm0);
      md_T[s][jc*2+1][tid] = 1.f/sqrtf(nrm1);
    }
  }
  __syncthreads();   // staging (Msh/rsd/resh/thr) + md_T visible to all

  // ---- phase 2: greedy iterations with per-sample active gating
  for (int it = 0; it < MAXIT; it++){
    // A: rn2 (tid<4), t = M.residual for active samples (tid 64..319)
    if (tid < SPB){
      float e = 0.f;
      for (int m = 0; m < MM; m++){
        float rr = rsd_re[tid][m], ri = rsd_im[tid][m];
        e += rr*rr + ri*ri;
      }
      rn2_sh[tid] = e;
    } else if (tid >= 64 && tid < 320){
      int q = tid - 64, s = q >> 6, n = q & 63;
      if (actsh[s]){                      // uniform per wave
        float tr = 0.f, ti = 0.f;
        #pragma unroll
        for (int m = 0; m < MM; m++){
          float mr = Msh_re[s][n][m], mi = Msh_im[s][n][m];
          float rr = rsd_re[s][m], ri = rsd_im[s][m];
          tr += mr*rr - mi*ri;            // t[n] = sum_m M[n,m]*r[m]
          ti += mr*ri + mi*rr;
        }
        tsh[n][2*s]   = tr;
        tsh[n][2*s+1] = ti;
      }
    }
    __syncthreads();

    // uniform per-sample active mask (benign idempotent race on actsh)
    bool a0 = actsh[0] && (rn2_sh[0] >= thr_sh[0]);
    bool a1 = actsh[1] && (rn2_sh[1] >= thr_sh[1]);
    bool a2 = actsh[2] && (rn2_sh[2] >= thr_sh[2]);
    bool a3 = actsh[3] && (rn2_sh[3] >= thr_sh[3]);
    if (tid < 4){
      int v = (tid==0) ? (int)a0 : (tid==1) ? (int)a1 : (tid==2) ? (int)a2 : (int)a3;
      actsh[tid] = v;
    }
    if (!(a0 || a1 || a2 || a3)) break;   // uniform: break BEFORE B work

    // B: g[s][j] = sum_n conj(W[n,a])*t[s,n], a = tid*4+j ; gated per sample
    float gr[SPB][JCOLS], gi[SPB][JCOLS];
    #pragma unroll
    for (int s = 0; s < SPB; s++)
      #pragma unroll
      for (int j = 0; j < JCOLS; j++){ gr[s][j]=0.f; gi[s][j]=0.f; }
    #pragma unroll 8
    for (int n = 0; n < NANT; n++){
      float4 t01 = *(const float4*)&tsh[n][0];
      float4 t23 = *(const float4*)&tsh[n][4];
      float4 wr = *(const float4*)(W_re + (size_t)n*DA + (tid<<2));
      float4 wi = *(const float4*)(W_im + (size_t)n*DA + (tid<<2));
      if (a0){
        gr[0][0] += wr.x*t01.x + wi.x*t01.y;  gi[0][0] += wr.x*t01.y - wi.x*t01.x;
        gr[0][1] += wr.y*t01.x + wi.y*t01.y;  gi[0][1] += wr.y*t01.y - wi.y*t01.x;
        gr[0][2] += wr.z*t01.x + wi.z*t01.y;  gi[0][2] += wr.z*t01.y - wi.z*t01.x;
        gr[0][3] += wr.w*t01.x + wi.w*t01.y;  gi[0][3] += wr.w*t01.y - wi.w*t01.x;
      }
      if (a1){
        gr[1][0] += wr.x*t01.z + wi.x*t01.w;  gi[1][0] += wr.x*t01.w - wi.x*t01.z;
        gr[1][1] += wr.y*t01.z + wi.y*t01.w;  gi[1][1] += wr.y*t01.w - wi.y*t01.z;
        gr[1][2] += wr.z*t01.z + wi.z*t01.w;  gi[1][2] += wr.z*t01.w - wi.z*t01.z;
        gr[1][3] += wr.w*t01.z + wi.w*t01.w;  gi[1][3] += wr.w*t01.w - wi.w*t01.z;
      }
      if (a2){
        gr[2][0] += wr.x*t23.x + wi.x*t23.y;  gi[2][0] += wr.x*t23.y - wi.x*t23.x;
        gr[2][1] += wr.y*t23.x + wi.y*t23.y;  gi[2][1] += wr.y*t23.y - wi.y*t23.x;
        gr[2][2] += wr.z*t23.x + wi.z*t23.y;  gi[2][2] += wr.z*t23.y - wi.z*t23.x;
        gr[2][3] += wr.w*t23.x + wi.w*t23.y;  gi[2][3] += wr.w*t23.y - wi.w*t23.x;
      }
      if (a3){
        gr[3][0] += wr.x*t23.z + wi.x*t23.w;  gi[3][0] += wr.x*t23.w - wi.x*t23.z;
        gr[3][1] += wr.y*t23.z + wi.y*t23.w;  gi[3][1] += wr.y*t23.w - wi.y*t23.z;
        gr[3][2] += wr.z*t23.z + wi.z*t23.w;  gi[3][2] += wr.z*t23.w - wi.z*t23.z;
        gr[3][3] += wr.w*t23.z + wi.w*t23.w;  gi[3][3] += wr.w*t23.w - wi.w*t23.z;
      }
    }

    // C: per-thread best (md_T conflict-free), gated; then wave reduce
    const bool acts[4] = {a0, a1, a2, a3};
    float bc2[SPB]; int bix[SPB];
    #pragma unroll
    for (int s = 0; s < SPB; s++){
      bc2[s] = -1.f; bix[s] = 0;
      if (acts[s]){
        float m0 = md_T[s][0][tid], m1 = md_T[s][1][tid];
        float m2 = md_T[s][2][tid], m3 = md_T[s][3][tid];
        float c0 = (gr[s][0]*gr[s][0] + gi[s][0]*gi[s][0]) * (m0*m0);
        float c1 = (gr[s][1]*gr[s][1] + gi[s][1]*gi[s][1]) * (m1*m1);
        float c2v = (gr[s][2]*gr[s][2] + gi[s][2]*gi[s][2]) * (m2*m2);
        float c3 = (gr[s][3]*gr[s][3] + gi[s][3]*gi[s][3]) * (m3*m3);
        float bc = c0; int bi = (tid<<2);
        if (c1 > bc){ bc = c1; bi = (tid<<2)+1; }
        if (c2v > bc){ bc = c2v; bi = (tid<<2)+2; }
        if (c3 > bc){ bc = c3; bi = (tid<<2)+3; }
        bc2[s] = bc; bix[s] = bi;
      }
    }
    #pragma unroll
    for (int s = 0; s < SPB; s++){
      if (acts[s]){
        #pragma unroll
        for (int off = 32; off; off >>= 1){
          float oc2 = __shfl_down(bc2[s], off);
          int   oix = __shfl_down(bix[s], off);
          if (oc2 > bc2[s] || (oc2 == bc2[s] && oix < bix[s])){ bc2[s]=oc2; bix[s]=oix; }
        }
      }
    }
    if ((tid & 63) == 0){
      int wid = tid >> 6;
      #pragma unroll
      for (int s = 0; s < SPB; s++){
        if (acts[s]){ red_c2[wid][s]=bc2[s]; red_ix[wid][s]=bix[s]; }
      }
    }
    __syncthreads();

    // D: per active sample (one wave each): cross-wave argmax + recompute val + einv
    if (tid < 256){
      int s = tid >> 6, lane = tid & 63;
      if (actsh[s]){                      // uniform per wave
        float c = (lane < 16) ? red_c2[lane][s] : -1.f;
        int   bi = (lane < 16) ? red_ix[lane][s] : 0x7FFFFFFF;
        #pragma unroll
        for (int off = 8; off; off >>= 1){
          float oc = __shfl_down(c, off);
          int   oi = __shfl_down(bi, off);
          if (oc > c || (oc == c && oi < bi)){ c = oc; bi = oi; }
        }
        int I = __shfl(bi, 0);
        float wr = W_re[(size_t)lane*DA + I], wi = W_im[(size_t)lane*DA + I];
        float tr = tsh[lane][2*s], ti = tsh[lane][2*s+1];
        float vr = wr*tr + wi*ti;
        float vi = wr*ti - wi*tr;
        float w2 = wr*wr + wi*wi;
        #pragma unroll
        for (int off = 32; off; off >>= 1){
          vr += __shfl_down(vr, off);
          vi += __shfl_down(vi, off);
          w2 += __shfl_down(w2, off);
        }
        if (lane == 0){
          float mdv = md_T[s][I & 3][I >> 2];
          sel_ix[s] = I;
          sel_vr[s] = vr*mdv;
          sel_vi[s] = vi*mdv;
          sel_md[s] = mdv;
          sel_ei[s] = rsqrtf(w2);
        }
      }
    }
    __syncthreads();

    // E: updates, gated per-sample
    if (tid < 64){
      int s = tid >> 4, m = tid & 15;
      if (actsh[s]){
        int I = sel_ix[s];
        float vr = sel_vr[s], vi = sel_vi[s], mdv = sel_md[s];
        float cre = 0.f, cim = 0.f;
        for (int n = 0; n < NANT; n++){
          float mr = Msh_re[s][n][m], mi = Msh_im[s][n][m];
          float wr = W_re[(size_t)n*DA + I], wi = W_im[(size_t)n*DA + I];
          cre += mr*wr + mi*wi;           // conj(M)*W
          cim += mr*wi - mi*wr;
        }
        cre *= mdv; cim *= mdv;
        rsd_re[s][m] -= vr*cre - vi*cim;
        rsd_im[s][m] -= vr*cim + vi*cre;
      }
    } else if (tid >= 64 && tid < 320){
      int q = tid - 64, s = q >> 6, n = q & 63;
      if (actsh[s]){
        int I = sel_ix[s];
        float vr = sel_vr[s], vi = sel_vi[s];
        float wr = W_re[(size_t)n*DA + I], wi = W_im[(size_t)n*DA + I];
        float ei = sel_ei[s];
        float er = wr*ei, em = wi*ei;     // E[:,I]
        resh_re[s][n] -= vr*er - vi*em;
        resh_im[s][n] -= vr*em + vi*er;
      }
    }
    __syncthreads();
  }

  // ---- epilogue: f32, six planes: re parts first (res, xhat, xhm), then im parts
  if (tid < 64){
    int s = tid >> 4, m = tid & 15; int b = b0 + s;
    float rr = rsd_re[s][m], ri = rsd_im[s][m];
    size_t base = (size_t)b*MM + m;                 // 0..16383
    if (base < outn)          out[base]          = rr;                        // res.re
    if (16384 + base < outn)  out[16384 + base]  = x_re[b*MM+m] - rr;         // xhat.re
    if (98304 + base < outn)  out[98304 + base]  = ri;                        // res.im
    if (114688 + base < outn) out[114688 + base] = x_im[b*MM+m] - ri;         // xhat.im
  } else if (tid >= 64 && tid < 320){
    int q = tid - 64, s = q >> 6, n = q & 63; int b = b0 + s;
    size_t base = (size_t)b*NANT + n;               // 0..65535
    if (32768 + base < outn)  out[32768 + base]  = xm_re[b*NANT+n] - resh_re[s][n];  // xhm.re
    if (131072 + base < outn) out[131072 + base] = xm_im[b*NANT+n] - resh_im[s][n];  // xhm.im
  }
}

extern "C" void kernel_launch(void* const* d_in, const int* in_sizes, int n_in,
                              void* d_out, int out_size, void* d_ws, size_t ws_size,
                              hipStream_t stream) {
  (void)in_sizes; (void)n_in; (void)d_ws; (void)ws_size;
  const float* x_re  = (const float*)d_in[0];
  const float* x_im  = (const float*)d_in[1];
  const float* xm_re = (const float*)d_in[2];
  const float* xm_im = (const float*)d_in[3];
  const float* M_re  = (const float*)d_in[4];
  const float* M_im  = (const float*)d_in[5];
  const float* W_re  = (const float*)d_in[6];
  const float* W_im  = (const float*)d_in[7];
  const float* sig   = (const float*)d_in[8];
  float* out = (float*)d_out;

  dim3 grid(NB_TOT / SPB), block(NTHR);
  hipLaunchKernelGGL(mpnet_kernel, grid, block, 0, stream,
                     x_re, x_im, xm_re, xm_im, M_re, M_im, W_re, W_im,
                     sig, out, out_size);
}

// Round 18
// 1417.565 us; speedup vs baseline: 1.4555x; 1.0804x over previous
//
#include <hip/hip_runtime.h>
#include <cstdint>
#include <cstddef>

#define NB_TOT 1024
#define NANT 64
#define MM 16
#define MPAD 17   // odd stride: per-lane strided LDS reads are 2-way (free)
#define DA 4096
#define MAXIT 20
#define SPB 4     // samples per block
#define NTHR 1024 // 16 waves
#define JCOLS 4   // consecutive cols per thread: a = tid*4 + j
#define L_CONST 10.0f

__global__ __launch_bounds__(NTHR, 4)
void mpnet_kernel(const float* __restrict__ x_re, const float* __restrict__ x_im,
                  const float* __restrict__ xm_re, const float* __restrict__ xm_im,
                  const float* __restrict__ M_re, const float* __restrict__ M_im,
                  const float* __restrict__ W_re, const float* __restrict__ W_im,
                  const float* __restrict__ sigma,
                  float* __restrict__ out, int outn_i)
{
  __shared__ float Msh_re[SPB][NANT][MPAD];    // 17.4 KB (phases A/DE)
  __shared__ float Msh_im[SPB][NANT][MPAD];    // 17.4 KB
  __shared__ float md_T[SPB][JCOLS][NTHR];     // 64 KB, transposed (conflict-free)
  __shared__ float tsh[NANT][8];               // 2 KB
  __shared__ float rsd_re[SPB][MM], rsd_im[SPB][MM];
  __shared__ float resh_re[SPB][NANT], resh_im[SPB][NANT];
  __shared__ float red_c2[16][SPB];
  __shared__ int   red_ix[16][SPB];
  __shared__ float rn2_sh[SPB], thr_sh[SPB];
  __shared__ int   actsh[SPB];

  const int tid = threadIdx.x;
  const int b0 = blockIdx.x * SPB;
  const size_t outn = (size_t)outn_i;

  // ---- init: stage M (for A/DE), residual(=x), res(=xm), thresholds
  for (int k2 = 0; k2 < 4; k2++){
    int idx = k2*NTHR + tid;            // 0..4095 = 4 samples x 64 n x 16 m
    int s = idx >> 10, rem = idx & 1023;
    int n = rem >> 4, m = rem & 15;
    Msh_re[s][n][m] = M_re[(size_t)b0*1024 + idx];
    Msh_im[s][n][m] = M_im[(size_t)b0*1024 + idx];
  }
  if (tid < SPB*MM){
    int s = tid >> 4, m = tid & 15;
    rsd_re[s][m] = x_re[(b0+s)*MM + m];
    rsd_im[s][m] = x_im[(b0+s)*MM + m];
  } else if (tid >= 64 && tid < 64 + SPB*NANT){
    int q = tid - 64, s = q >> 6, n = q & 63;
    resh_re[s][n] = xm_re[(b0+s)*NANT + n];
    resh_im[s][n] = xm_im[(b0+s)*NANT + n];
  } else if (tid >= 448 && tid < 448 + SPB){
    int s = tid - 448;
    float sg = sigma[b0+s];
    thr_sh[s] = ((sg*sg) * (float)NANT) * L_CONST;
    actsh[s] = 1;
  }
  // no barrier yet: phase 1 reads M from GLOBAL (uniform addrs) and own W cols

  // ---- phase 1: md = 1/||M_D col||; single-col passes, mc merged (32 accum regs)
  #pragma unroll
  for (int s = 0; s < SPB; s++){
    const float* MrS = M_re + (size_t)(b0+s)*1024;   // [n][m], uniform base
    const float* MiS = M_im + (size_t)(b0+s)*1024;
    #pragma unroll
    for (int jc = 0; jc < JCOLS; jc++){  // col = tid*4 + jc
      const int col = (tid<<2) + jc;
      float cr[MM], ci[MM];
      #pragma unroll
      for (int q = 0; q < MM; q++){ cr[q]=0.f; ci[q]=0.f; }
      #pragma unroll 2
      for (int n = 0; n < NANT; n++){
        float wr = W_re[(size_t)n*DA + col];
        float wi = W_im[(size_t)n*DA + col];
        const float* Mr = MrS + n*MM;    // uniform across lanes
        const float* Mi = MiS + n*MM;
        #pragma unroll
        for (int q2 = 0; q2 < 4; q2++){
          float4 m4r = *(const float4*)(Mr + q2*4);   // uniform 16B loads
          float4 m4i = *(const float4*)(Mi + q2*4);
          cr[q2*4+0] += m4r.x*wr + m4i.x*wi;  ci[q2*4+0] += m4r.x*wi - m4i.x*wr;
          cr[q2*4+1] += m4r.y*wr + m4i.y*wi;  ci[q2*4+1] += m4r.y*wi - m4i.y*wr;
          cr[q2*4+2] += m4r.z*wr + m4i.z*wi;  ci[q2*4+2] += m4r.z*wi - m4i.z*wr;
          cr[q2*4+3] += m4r.w*wr + m4i.w*wi;  ci[q2*4+3] += m4r.w*wi - m4i.w*wr;
        }
      }
      float nrm = 0.f;
      #pragma unroll
      for (int q = 0; q < MM; q++) nrm += cr[q]*cr[q] + ci[q]*ci[q];
      md_T[s][jc][tid] = 1.f/sqrtf(nrm);
    }
  }
  __syncthreads();   // staging + md_T visible

  // ---- phase 2: greedy iterations with per-sample active gating
  for (int it = 0; it < MAXIT; it++){
    // A: rn2 (tid<4), t = M.residual for active samples (tid 64..319)
    if (tid < SPB){
      float e = 0.f;
      #pragma unroll
      for (int m = 0; m < MM; m++){
        float rr = rsd_re[tid][m], ri = rsd_im[tid][m];
        e += rr*rr + ri*ri;
      }
      rn2_sh[tid] = e;
    } else if (tid >= 64 && tid < 320){
      int q = tid - 64, s = q >> 6, n = q & 63;
      if (actsh[s]){                      // uniform per wave
        float tr = 0.f, ti = 0.f;
        #pragma unroll
        for (int m = 0; m < MM; m++){
          float mr = Msh_re[s][n][m], mi = Msh_im[s][n][m];
          float rr = rsd_re[s][m], ri = rsd_im[s][m];
          tr += mr*rr - mi*ri;            // t[n] = sum_m M[n,m]*r[m]
          ti += mr*ri + mi*rr;
        }
        tsh[n][2*s]   = tr;
        tsh[n][2*s+1] = ti;
      }
    }
    __syncthreads();

    // uniform per-sample active mask (benign idempotent race on actsh)
    bool a0 = actsh[0] && (rn2_sh[0] >= thr_sh[0]);
    bool a1 = actsh[1] && (rn2_sh[1] >= thr_sh[1]);
    bool a2 = actsh[2] && (rn2_sh[2] >= thr_sh[2]);
    bool a3 = actsh[3] && (rn2_sh[3] >= thr_sh[3]);
    if (tid < 4){
      int v = (tid==0) ? (int)a0 : (tid==1) ? (int)a1 : (tid==2) ? (int)a2 : (int)a3;
      actsh[tid] = v;
    }
    if (!(a0 || a1 || a2 || a3)) break;   // uniform: break BEFORE B work

    // B: g[s][j] = sum_n conj(W[n,a])*t[s,n], a = tid*4+j ; gated per sample
    float gr[SPB][JCOLS], gi[SPB][JCOLS];
    #pragma unroll
    for (int s = 0; s < SPB; s++)
      #pragma unroll
      for (int j = 0; j < JCOLS; j++){ gr[s][j]=0.f; gi[s][j]=0.f; }
    #pragma unroll 8
    for (int n = 0; n < NANT; n++){
      float4 t01 = *(const float4*)&tsh[n][0];
      float4 t23 = *(const float4*)&tsh[n][4];
      float4 wr = *(const float4*)(W_re + (size_t)n*DA + (tid<<2));
      float4 wi = *(const float4*)(W_im + (size_t)n*DA + (tid<<2));
      if (a0){
        gr[0][0] += wr.x*t01.x + wi.x*t01.y;  gi[0][0] += wr.x*t01.y - wi.x*t01.x;
        gr[0][1] += wr.y*t01.x + wi.y*t01.y;  gi[0][1] += wr.y*t01.y - wi.y*t01.x;
        gr[0][2] += wr.z*t01.x + wi.z*t01.y;  gi[0][2] += wr.z*t01.y - wi.z*t01.x;
        gr[0][3] += wr.w*t01.x + wi.w*t01.y;  gi[0][3] += wr.w*t01.y - wi.w*t01.x;
      }
      if (a1){
        gr[1][0] += wr.x*t01.z + wi.x*t01.w;  gi[1][0] += wr.x*t01.w - wi.x*t01.z;
        gr[1][1] += wr.y*t01.z + wi.y*t01.w;  gi[1][1] += wr.y*t01.w - wi.y*t01.z;
        gr[1][2] += wr.z*t01.z + wi.z*t01.w;  gi[1][2] += wr.z*t01.w - wi.z*t01.z;
        gr[1][3] += wr.w*t01.z + wi.w*t01.w;  gi[1][3] += wr.w*t01.w - wi.w*t01.z;
      }
      if (a2){
        gr[2][0] += wr.x*t23.x + wi.x*t23.y;  gi[2][0] += wr.x*t23.y - wi.x*t23.x;
        gr[2][1] += wr.y*t23.x + wi.y*t23.y;  gi[2][1] += wr.y*t23.y - wi.y*t23.x;
        gr[2][2] += wr.z*t23.x + wi.z*t23.y;  gi[2][2] += wr.z*t23.y - wi.z*t23.x;
        gr[2][3] += wr.w*t23.x + wi.w*t23.y;  gi[2][3] += wr.w*t23.y - wi.w*t23.x;
      }
      if (a3){
        gr[3][0] += wr.x*t23.z + wi.x*t23.w;  gi[3][0] += wr.x*t23.w - wi.x*t23.z;
        gr[3][1] += wr.y*t23.z + wi.y*t23.w;  gi[3][1] += wr.y*t23.w - wi.y*t23.z;
        gr[3][2] += wr.z*t23.z + wi.z*t23.w;  gi[3][2] += wr.z*t23.w - wi.z*t23.z;
        gr[3][3] += wr.w*t23.z + wi.w*t23.w;  gi[3][3] += wr.w*t23.w - wi.w*t23.z;
      }
    }

    // C: per-thread best (md_T conflict-free), gated; then wave reduce
    const bool acts[4] = {a0, a1, a2, a3};
    float bc2[SPB]; int bix[SPB];
    #pragma unroll
    for (int s = 0; s < SPB; s++){
      bc2[s] = -1.f; bix[s] = 0;
      if (acts[s]){
        float m0 = md_T[s][0][tid], m1 = md_T[s][1][tid];
        float m2 = md_T[s][2][tid], m3 = md_T[s][3][tid];
        float c0 = (gr[s][0]*gr[s][0] + gi[s][0]*gi[s][0]) * (m0*m0);
        float c1 = (gr[s][1]*gr[s][1] + gi[s][1]*gi[s][1]) * (m1*m1);
        float c2v = (gr[s][2]*gr[s][2] + gi[s][2]*gi[s][2]) * (m2*m2);
        float c3 = (gr[s][3]*gr[s][3] + gi[s][3]*gi[s][3]) * (m3*m3);
        float bc = c0; int bi = (tid<<2);
        if (c1 > bc){ bc = c1; bi = (tid<<2)+1; }
        if (c2v > bc){ bc = c2v; bi = (tid<<2)+2; }
        if (c3 > bc){ bc = c3; bi = (tid<<2)+3; }
        bc2[s] = bc; bix[s] = bi;
      }
    }
    #pragma unroll
    for (int s = 0; s < SPB; s++){
      if (acts[s]){
        #pragma unroll
        for (int off = 32; off; off >>= 1){
          float oc2 = __shfl_down(bc2[s], off);
          int   oix = __shfl_down(bix[s], off);
          if (oc2 > bc2[s] || (oc2 == bc2[s] && oix < bix[s])){ bc2[s]=oc2; bix[s]=oix; }
        }
      }
    }
    if ((tid & 63) == 0){
      int wid = tid >> 6;
      #pragma unroll
      for (int s = 0; s < SPB; s++){
        if (acts[s]){ red_c2[wid][s]=bc2[s]; red_ix[wid][s]=bix[s]; }
      }
    }
    __syncthreads();

    // D+E fused: wave s (s<4, active) does argmax + val + einv + res & rsd updates
    if (tid < 256){
      int s = tid >> 6, lane = tid & 63;
      if (actsh[s]){                      // uniform per wave
        float c = (lane < 16) ? red_c2[lane][s] : -1.f;
        int   bi = (lane < 16) ? red_ix[lane][s] : 0x7FFFFFFF;
        #pragma unroll
        for (int off = 8; off; off >>= 1){
          float oc = __shfl_xor(c, off);
          int   oi = __shfl_xor(bi, off);
          if (oc > c || (oc == c && oi < bi)){ c = oc; bi = oi; }
        }
        int I = __shfl(bi, 0);
        // val = sum_n conj(W[n,I]) t[s,n]; E-col norm; lane = n
        float wr = W_re[(size_t)lane*DA + I], wi = W_im[(size_t)lane*DA + I];
        float tr = tsh[lane][2*s], ti = tsh[lane][2*s+1];
        float vr = wr*tr + wi*ti;
        float vi = wr*ti - wi*tr;
        float w2 = wr*wr + wi*wi;
        #pragma unroll
        for (int off = 32; off; off >>= 1){
          vr += __shfl_xor(vr, off);
          vi += __shfl_xor(vi, off);
          w2 += __shfl_xor(w2, off);
        }
        float mdv = md_T[s][I & 3][I >> 2];    // broadcast LDS read
        float val_r = vr*mdv, val_i = vi*mdv;
        float einv = rsqrtf(w2);
        // res update: all 64 lanes (lane = n), reuse wr/wi
        float er = wr*einv, em = wi*einv;      // E[:,I]
        resh_re[s][lane] -= val_r*er - val_i*em;
        resh_im[s][lane] -= val_r*em + val_i*er;
        // rsd update: 16 wave-parallel column dots (lane = n), lane m stores
        for (int m = 0; m < MM; m++){
          float mr = Msh_re[s][lane][m], mi = Msh_im[s][lane][m];
          float pr = mr*wr + mi*wi;            // conj(M[n,m])*W[n,I]
          float pi = mr*wi - mi*wr;
          #pragma unroll
          for (int off = 32; off; off >>= 1){
            pr += __shfl_xor(pr, off);
            pi += __shfl_xor(pi, off);
          }
          if (lane == m){
            float col_r = pr*mdv, col_i = pi*mdv;
            rsd_re[s][m] -= val_r*col_r - val_i*col_i;
            rsd_im[s][m] -= val_r*col_i + val_i*col_r;
          }
        }
      }
    }
    __syncthreads();
  }

  // ---- epilogue: f32, six planes: re parts first (res, xhat, xhm), then im parts
  if (tid < 64){
    int s = tid >> 4, m = tid & 15; int b = b0 + s;
    float rr = rsd_re[s][m], ri = rsd_im[s][m];
    size_t base = (size_t)b*MM + m;                 // 0..16383
    if (base < outn)          out[base]          = rr;                        // res.re
    if (16384 + base < outn)  out[16384 + base]  = x_re[b*MM+m] - rr;         // xhat.re
    if (98304 + base < outn)  out[98304 + base]  = ri;                        // res.im
    if (114688 + base < outn) out[114688 + base] = x_im[b*MM+m] - ri;         // xhat.im
  } else if (tid >= 64 && tid < 320){
    int q = tid - 64, s = q >> 6, n = q & 63; int b = b0 + s;
    size_t base = (size_t)b*NANT + n;               // 0..65535
    if (32768 + base < outn)  out[32768 + base]  = xm_re[b*NANT+n] - resh_re[s][n];  // xhm.re
    if (131072 + base < outn) out[131072 + base] = xm_im[b*NANT+n] - resh_im[s][n];  // xhm.im
  }
}

extern "C" void kernel_launch(void* const* d_in, const int* in_sizes, int n_in,
                              void* d_out, int out_size, void* d_ws, size_t ws_size,
                              hipStream_t stream) {
  (void)in_sizes; (void)n_in; (void)d_ws; (void)ws_size;
  const float* x_re  = (const float*)d_in[0];
  const float* x_im  = (const float*)d_in[1];
  const float* xm_re = (const float*)d_in[2];
  const float* xm_im = (const float*)d_in[3];
  const float* M_re  = (const float*)d_in[4];
  const float* M_im  = (const float*)d_in[5];
  const float* W_re  = (const float*)d_in[6];
  const float* W_im  = (const float*)d_in[7];
  const float* sig   = (const float*)d_in[8];
  float* out = (float*)d_out;

  dim3 grid(NB_TOT / SPB), block(NTHR);
  hipLaunchKernelGGL(mpnet_kernel, grid, block, 0, stream,
                     x_re, x_im, xm_re, xm_im, M_re, M_im, W_re, W_im,
                     sig, out, out_size);
}